// Round 1
// baseline (894.203 us; speedup 1.0000x reference)
//
#include <hip/hip_runtime.h>
#include <math.h>

#define NS 0.01f

__device__ __forceinline__ float lrelu(float v) { return v > 0.f ? v : NS * v; }

// ---------------- prep MLP: h = tanh(lrelu(x@W1+b1)@W2+b2), x:[N,16] ----------------
__global__ void __launch_bounds__(256) prep_kernel(
    const float* __restrict__ x,
    const float* __restrict__ W1, const float* __restrict__ b1,
    const float* __restrict__ W2, const float* __restrict__ b2,
    float* __restrict__ h, int N)
{
    __shared__ float sW1[16 * 64];
    __shared__ float sW2[64 * 64];
    __shared__ float sb1[64], sb2[64];
    __shared__ float sin_[4][16];
    __shared__ float smid[4][64];
    const int t = threadIdx.x;
    for (int i = t; i < 16 * 64; i += 256) sW1[i] = W1[i];
    for (int i = t; i < 64 * 64; i += 256) sW2[i] = W2[i];
    if (t < 64) { sb1[t] = b1[t]; sb2[t] = b2[t]; }
    __syncthreads();
    const int local = t >> 6, j = t & 63;
    for (int n0 = blockIdx.x * 4; n0 < N; n0 += gridDim.x * 4) {
        const int n = n0 + local;
        if (j < 16 && n < N) sin_[local][j] = x[(size_t)n * 16 + j];
        __syncthreads();
        if (n < N) {
            float acc = sb1[j];
            #pragma unroll
            for (int i = 0; i < 16; ++i) acc += sin_[local][i] * sW1[i * 64 + j];
            smid[local][j] = lrelu(acc);
        }
        __syncthreads();
        if (n < N) {
            float acc = sb2[j];
            #pragma unroll
            for (int i = 0; i < 64; ++i) acc += smid[local][i] * sW2[i * 64 + j];
            h[(size_t)n * 64 + j] = tanhf(acc);
        }
        __syncthreads();
    }
}

// ---------------- edge aggregation: agg[dst] += relu(h[src] + ew*We + be) ----------------
__global__ void __launch_bounds__(256) edge_kernel(
    const float* __restrict__ h,
    const int* __restrict__ src, const int* __restrict__ dst,
    const float* __restrict__ ew,
    const float* __restrict__ We_k, const float* __restrict__ be_k,
    float* __restrict__ agg, int E)
{
    const int tid = blockIdx.x * 256 + threadIdx.x;
    const int total = E * 64;
    if (tid >= total) return;
    const int e = tid >> 6;
    const int f = tid & 63;
    const int s = src[e];
    const float m = h[(size_t)s * 64 + f] + ew[e] * We_k[f] + be_k[f];
    if (m > 0.f) {
        const int d = dst[e];
        atomicAdd(&agg[(size_t)d * 64 + f], m);
    }
}

// ---------------- conv MLP: hout = tanh(lrelu((agg+hin)@W0+b0)@W1+b1) ----------------
__global__ void __launch_bounds__(256) mlp_kernel(
    const float* __restrict__ agg, const float* __restrict__ hin,
    const float* __restrict__ W0, const float* __restrict__ b0,
    const float* __restrict__ W1, const float* __restrict__ b1,
    float* __restrict__ hout, int N)
{
    __shared__ float sW0[64 * 64];
    __shared__ float sW1[64 * 64];
    __shared__ float sb0[64], sb1[64];
    __shared__ float sz[4][64];
    __shared__ float sm[4][64];
    const int t = threadIdx.x;
    for (int i = t; i < 64 * 64; i += 256) { sW0[i] = W0[i]; sW1[i] = W1[i]; }
    if (t < 64) { sb0[t] = b0[t]; sb1[t] = b1[t]; }
    __syncthreads();
    const int local = t >> 6, j = t & 63;
    for (int n0 = blockIdx.x * 4; n0 < N; n0 += gridDim.x * 4) {
        const int n = n0 + local;
        if (n < N) sz[local][j] = agg[(size_t)n * 64 + j] + hin[(size_t)n * 64 + j];
        __syncthreads();
        if (n < N) {
            float acc = sb0[j];
            #pragma unroll
            for (int i = 0; i < 64; ++i) acc += sz[local][i] * sW0[i * 64 + j];
            sm[local][j] = lrelu(acc);
        }
        __syncthreads();
        if (n < N) {
            float acc = sb1[j];
            #pragma unroll
            for (int i = 0; i < 64; ++i) acc += sm[local][i] * sW1[i * 64 + j];
            hout[(size_t)n * 64 + j] = tanhf(acc);
        }
        __syncthreads();
    }
}

// ---------------- post MLP: out = tanh(lrelu(h@W0+b0)@W1+b1), out:[N,32] ----------------
__global__ void __launch_bounds__(256) post_kernel(
    const float* __restrict__ h,
    const float* __restrict__ W0, const float* __restrict__ b0,
    const float* __restrict__ W1, const float* __restrict__ b1,
    float* __restrict__ out, int N)
{
    __shared__ float sW0[64 * 64];
    __shared__ float sW1[64 * 32];
    __shared__ float sb0[64], sb1[32];
    __shared__ float sh[4][64];
    __shared__ float sz[4][64];
    const int t = threadIdx.x;
    for (int i = t; i < 64 * 64; i += 256) sW0[i] = W0[i];
    for (int i = t; i < 64 * 32; i += 256) sW1[i] = W1[i];
    if (t < 64) sb0[t] = b0[t];
    if (t < 32) sb1[t] = b1[t];
    __syncthreads();
    const int local = t >> 6, j = t & 63;
    for (int n0 = blockIdx.x * 4; n0 < N; n0 += gridDim.x * 4) {
        const int n = n0 + local;
        if (n < N) sh[local][j] = h[(size_t)n * 64 + j];
        __syncthreads();
        if (n < N) {
            float acc = sb0[j];
            #pragma unroll
            for (int i = 0; i < 64; ++i) acc += sh[local][i] * sW0[i * 64 + j];
            sz[local][j] = lrelu(acc);
        }
        __syncthreads();
        if (n < N && j < 32) {
            float acc = sb1[j];
            #pragma unroll
            for (int i = 0; i < 64; ++i) acc += sz[local][i] * sW1[i * 32 + j];
            out[(size_t)n * 32 + j] = tanhf(acc);
        }
        __syncthreads();
    }
}

extern "C" void kernel_launch(void* const* d_in, const int* in_sizes, int n_in,
                              void* d_out, int out_size, void* d_ws, size_t ws_size,
                              hipStream_t stream) {
    const float* x     = (const float*)d_in[0];
    const int*   ei    = (const int*)d_in[1];
    const float* ew    = (const float*)d_in[2];
    const float* Wp_in = (const float*)d_in[3];
    const float* bp_in = (const float*)d_in[4];
    const float* Wp_h  = (const float*)d_in[5];
    const float* bp_h  = (const float*)d_in[6];
    const float* We    = (const float*)d_in[7];   // [3,1,64]
    const float* be    = (const float*)d_in[8];   // [3,64]
    const float* Wm0   = (const float*)d_in[9];   // [3,64,64]
    const float* bm0   = (const float*)d_in[10];  // [3,64]
    const float* Wm1   = (const float*)d_in[11];  // [3,64,64]
    const float* bm1   = (const float*)d_in[12];  // [3,64]
    const float* Wq0   = (const float*)d_in[13];
    const float* bq0   = (const float*)d_in[14];
    const float* Wq1   = (const float*)d_in[15];
    const float* bq1   = (const float*)d_in[16];
    float* out = (float*)d_out;

    const int N = in_sizes[0] / 16;
    const int E = in_sizes[2];
    const int* src = ei;
    const int* dst = ei + E;

    float* hA  = (float*)d_ws;
    float* hB  = hA + (size_t)N * 64;
    float* agg = hB + (size_t)N * 64;

    prep_kernel<<<2048, 256, 0, stream>>>(x, Wp_in, bp_in, Wp_h, bp_h, hA, N);

    float* hin = hA;
    float* hout = hB;
    const int etotal = E * 64;
    const int eblocks = (etotal + 255) / 256;
    for (int k = 0; k < 3; ++k) {
        hipMemsetAsync(agg, 0, (size_t)N * 64 * sizeof(float), stream);
        edge_kernel<<<eblocks, 256, 0, stream>>>(
            hin, src, dst, ew, We + (size_t)k * 64, be + (size_t)k * 64, agg, E);
        mlp_kernel<<<2048, 256, 0, stream>>>(
            agg, hin, Wm0 + (size_t)k * 4096, bm0 + (size_t)k * 64,
            Wm1 + (size_t)k * 4096, bm1 + (size_t)k * 64, hout, N);
        float* tmp = hin; hin = hout; hout = tmp;
    }

    post_kernel<<<2048, 256, 0, stream>>>(hin, Wq0, bq0, Wq1, bq1, out, N);
}

// Round 2
// 884.491 us; speedup vs baseline: 1.0110x; 1.0110x over previous
//
#include <hip/hip_runtime.h>
#include <math.h>

#define NS 0.01f

__device__ __forceinline__ float lrelu(float v) { return v > 0.f ? v : NS * v; }

// ---------------- prep MLP: h = tanh(lrelu(x@W1+b1)@W2+b2), x:[N,16] ----------------
__global__ void __launch_bounds__(256) prep_kernel(
    const float* __restrict__ x,
    const float* __restrict__ W1, const float* __restrict__ b1,
    const float* __restrict__ W2, const float* __restrict__ b2,
    float* __restrict__ h, int N)
{
    __shared__ float sW1[16 * 64];
    __shared__ float sW2[64 * 64];
    __shared__ float sb1[64], sb2[64];
    __shared__ float sin_[4][16];
    __shared__ float smid[4][64];
    const int t = threadIdx.x;
    for (int i = t; i < 16 * 64; i += 256) sW1[i] = W1[i];
    for (int i = t; i < 64 * 64; i += 256) sW2[i] = W2[i];
    if (t < 64) { sb1[t] = b1[t]; sb2[t] = b2[t]; }
    __syncthreads();
    const int local = t >> 6, j = t & 63;
    for (int n0 = blockIdx.x * 4; n0 < N; n0 += gridDim.x * 4) {
        const int n = n0 + local;
        if (j < 16 && n < N) sin_[local][j] = x[(size_t)n * 16 + j];
        __syncthreads();
        if (n < N) {
            float acc = sb1[j];
            #pragma unroll
            for (int i = 0; i < 16; ++i) acc += sin_[local][i] * sW1[i * 64 + j];
            smid[local][j] = lrelu(acc);
        }
        __syncthreads();
        if (n < N) {
            float acc = sb2[j];
            #pragma unroll
            for (int i = 0; i < 64; ++i) acc += smid[local][i] * sW2[i * 64 + j];
            h[(size_t)n * 64 + j] = tanhf(acc);
        }
        __syncthreads();
    }
}

// ---------------- CSR build ----------------
__global__ void __launch_bounds__(256) hist_kernel(
    const int* __restrict__ dst, int* __restrict__ deg, int E)
{
    const int e = blockIdx.x * 256 + threadIdx.x;
    if (e < E) atomicAdd(&deg[dst[e]], 1);
}

__global__ void __launch_bounds__(1024) scan_kernel(
    const int* __restrict__ deg, int* __restrict__ rowstart,
    int* __restrict__ cursor, int N)
{
    __shared__ int part[1024];
    const int t = threadIdx.x;
    const int chunk = (N + 1023) / 1024;
    const int base = t * chunk;
    int sum = 0;
    for (int i = 0; i < chunk; ++i) {
        const int idx = base + i;
        if (idx < N) sum += deg[idx];
    }
    part[t] = sum;
    __syncthreads();
    for (int off = 1; off < 1024; off <<= 1) {
        const int v = (t >= off) ? part[t - off] : 0;
        __syncthreads();
        part[t] += v;
        __syncthreads();
    }
    int run = (t == 0) ? 0 : part[t - 1];
    for (int i = 0; i < chunk; ++i) {
        const int idx = base + i;
        if (idx < N) {
            rowstart[idx] = run;
            cursor[idx]   = run;
            run += deg[idx];
        }
    }
    if (t == 1023) rowstart[N] = part[1023];
}

__global__ void __launch_bounds__(256) fill_kernel(
    const int* __restrict__ src, const int* __restrict__ dst,
    const float* __restrict__ ew,
    int* __restrict__ cursor, int* __restrict__ csr_src,
    float* __restrict__ csr_w, int E)
{
    const int e = blockIdx.x * 256 + threadIdx.x;
    if (e < E) {
        const int d = dst[e];
        const int p = atomicAdd(&cursor[d], 1);
        csr_src[p] = src[e];
        csr_w[p]   = ew[e];
    }
}

// ------- fused conv: per-node CSR aggregation (no atomics) + 2-layer MLP -------
__global__ void __launch_bounds__(256) conv_kernel(
    const float* __restrict__ h,
    const int* __restrict__ rowstart,
    const int* __restrict__ csr_src, const float* __restrict__ csr_w,
    const float* __restrict__ We_k, const float* __restrict__ be_k,
    const float* __restrict__ W0, const float* __restrict__ b0,
    const float* __restrict__ W1, const float* __restrict__ b1,
    float* __restrict__ hout, int N)
{
    __shared__ float sW0[64 * 64];
    __shared__ float sW1[64 * 64];
    __shared__ float sb0[64], sb1[64];
    __shared__ float sz[4][64];
    __shared__ float sm[4][64];
    const int t = threadIdx.x;
    for (int i = t; i < 4096; i += 256) { sW0[i] = W0[i]; sW1[i] = W1[i]; }
    if (t < 64) { sb0[t] = b0[t]; sb1[t] = b1[t]; }
    __syncthreads();
    const int local = t >> 6, j = t & 63;
    const float wej = We_k[j], bej = be_k[j];
    for (int n0 = blockIdx.x * 4; n0 < N; n0 += gridDim.x * 4) {
        const int n = n0 + local;
        if (n < N) {
            float acc = 0.f;
            const int start = rowstart[n], end = rowstart[n + 1];
            for (int p = start; p < end; ++p) {
                const int s = csr_src[p];
                const float m = h[(size_t)s * 64 + j] + csr_w[p] * wej + bej;
                acc += fmaxf(m, 0.f);
            }
            sz[local][j] = acc + h[(size_t)n * 64 + j];
        }
        __syncthreads();
        if (n < N) {
            float acc = sb0[j];
            #pragma unroll
            for (int i = 0; i < 64; ++i) acc += sz[local][i] * sW0[i * 64 + j];
            sm[local][j] = lrelu(acc);
        }
        __syncthreads();
        if (n < N) {
            float acc = sb1[j];
            #pragma unroll
            for (int i = 0; i < 64; ++i) acc += sm[local][i] * sW1[i * 64 + j];
            hout[(size_t)n * 64 + j] = tanhf(acc);
        }
        __syncthreads();
    }
}

// ---------------- post MLP: out = tanh(lrelu(h@W0+b0)@W1+b1), out:[N,32] ----------------
__global__ void __launch_bounds__(256) post_kernel(
    const float* __restrict__ h,
    const float* __restrict__ W0, const float* __restrict__ b0,
    const float* __restrict__ W1, const float* __restrict__ b1,
    float* __restrict__ out, int N)
{
    __shared__ float sW0[64 * 64];
    __shared__ float sW1[64 * 32];
    __shared__ float sb0[64], sb1[32];
    __shared__ float sh[4][64];
    __shared__ float sz[4][64];
    const int t = threadIdx.x;
    for (int i = t; i < 64 * 64; i += 256) sW0[i] = W0[i];
    for (int i = t; i < 64 * 32; i += 256) sW1[i] = W1[i];
    if (t < 64) sb0[t] = b0[t];
    if (t < 32) sb1[t] = b1[t];
    __syncthreads();
    const int local = t >> 6, j = t & 63;
    for (int n0 = blockIdx.x * 4; n0 < N; n0 += gridDim.x * 4) {
        const int n = n0 + local;
        if (n < N) sh[local][j] = h[(size_t)n * 64 + j];
        __syncthreads();
        if (n < N) {
            float acc = sb0[j];
            #pragma unroll
            for (int i = 0; i < 64; ++i) acc += sh[local][i] * sW0[i * 64 + j];
            sz[local][j] = lrelu(acc);
        }
        __syncthreads();
        if (n < N && j < 32) {
            float acc = sb1[j];
            #pragma unroll
            for (int i = 0; i < 64; ++i) acc += sz[local][i] * sW1[i * 32 + j];
            out[(size_t)n * 32 + j] = tanhf(acc);
        }
        __syncthreads();
    }
}

extern "C" void kernel_launch(void* const* d_in, const int* in_sizes, int n_in,
                              void* d_out, int out_size, void* d_ws, size_t ws_size,
                              hipStream_t stream) {
    const float* x     = (const float*)d_in[0];
    const int*   ei    = (const int*)d_in[1];
    const float* ew    = (const float*)d_in[2];
    const float* Wp_in = (const float*)d_in[3];
    const float* bp_in = (const float*)d_in[4];
    const float* Wp_h  = (const float*)d_in[5];
    const float* bp_h  = (const float*)d_in[6];
    const float* We    = (const float*)d_in[7];   // [3,1,64]
    const float* be    = (const float*)d_in[8];   // [3,64]
    const float* Wm0   = (const float*)d_in[9];   // [3,64,64]
    const float* bm0   = (const float*)d_in[10];  // [3,64]
    const float* Wm1   = (const float*)d_in[11];  // [3,64,64]
    const float* bm1   = (const float*)d_in[12];  // [3,64]
    const float* Wq0   = (const float*)d_in[13];
    const float* bq0   = (const float*)d_in[14];
    const float* Wq1   = (const float*)d_in[15];
    const float* bq1   = (const float*)d_in[16];
    float* out = (float*)d_out;

    const int N = in_sizes[0] / 16;
    const int E = in_sizes[2];
    const int* src = ei;
    const int* dst = ei + E;

    // workspace layout
    float* hA       = (float*)d_ws;                 // N*64
    float* hB       = hA + (size_t)N * 64;          // N*64
    int*   deg      = (int*)(hB + (size_t)N * 64);  // N
    int*   rowstart = deg + N;                      // N+1
    int*   cursor   = rowstart + N + 1;             // N
    int*   csr_src  = cursor + N;                   // E
    float* csr_w    = (float*)(csr_src + E);        // E

    const int eblocks = (E + 255) / 256;

    // CSR build (once; reused by all 3 convs)
    hipMemsetAsync(deg, 0, (size_t)N * sizeof(int), stream);
    hist_kernel<<<eblocks, 256, 0, stream>>>(dst, deg, E);
    scan_kernel<<<1, 1024, 0, stream>>>(deg, rowstart, cursor, N);
    fill_kernel<<<eblocks, 256, 0, stream>>>(src, dst, ew, cursor, csr_src, csr_w, E);

    prep_kernel<<<2048, 256, 0, stream>>>(x, Wp_in, bp_in, Wp_h, bp_h, hA, N);

    float* hin = hA;
    float* hout = hB;
    for (int k = 0; k < 3; ++k) {
        conv_kernel<<<2048, 256, 0, stream>>>(
            hin, rowstart, csr_src, csr_w,
            We + (size_t)k * 64, be + (size_t)k * 64,
            Wm0 + (size_t)k * 4096, bm0 + (size_t)k * 64,
            Wm1 + (size_t)k * 4096, bm1 + (size_t)k * 64, hout, N);
        float* tmp = hin; hin = hout; hout = tmp;
    }

    post_kernel<<<2048, 256, 0, stream>>>(hin, Wq0, bq0, Wq1, bq1, out, N);
}

// Round 4
// 424.272 us; speedup vs baseline: 2.1076x; 2.0847x over previous
//
#include <hip/hip_runtime.h>
#include <math.h>

#define NS 0.01f

__device__ __forceinline__ float lrelu(float v) { return v > 0.f ? v : NS * v; }

// broadcast lane i's value of v to all lanes.
// CAUTION: must be called with all 64 lanes active and v computed by all lanes,
// otherwise the compiler may sink v's computation into a divergent region and
// readlane returns garbage (round-3 bug).
__device__ __forceinline__ float lane_bcast(float v, int i) {
    return __uint_as_float(__builtin_amdgcn_readlane(__float_as_uint(v), i));
}

// ---------------- prep MLP: h = tanh(lrelu(x@W1+b1)@W2+b2), x:[N,16] ----------------
// one wave per node; lane j = feature j; activations broadcast via readlane
__global__ void __launch_bounds__(512) prep_kernel(
    const float* __restrict__ x,
    const float* __restrict__ W1, const float* __restrict__ b1,
    const float* __restrict__ W2, const float* __restrict__ b2,
    float* __restrict__ h, int N)
{
    __shared__ float sW1[16 * 64];
    __shared__ float sW2[64 * 64];
    __shared__ float sb1[64], sb2[64];
    const int t = threadIdx.x;
    for (int i = t; i < 16 * 64; i += 512) sW1[i] = W1[i];
    for (int i = t; i < 64 * 64; i += 512) sW2[i] = W2[i];
    if (t < 64) { sb1[t] = b1[t]; sb2[t] = b2[t]; }
    __syncthreads();
    const int wave = t >> 6, j = t & 63;
    const int n = blockIdx.x * 8 + wave;
    if (n >= N) return;   // wave-uniform
    // unconditional load (clamped index) -> all lanes active for readlane
    const float xv = x[(size_t)n * 16 + (j & 15)];
    float a = sb1[j];
    #pragma unroll
    for (int i = 0; i < 16; ++i) a += lane_bcast(xv, i) * sW1[i * 64 + j];
    const float mid = lrelu(a);
    float a2 = sb2[j];
    #pragma unroll
    for (int i = 0; i < 64; ++i) a2 += lane_bcast(mid, i) * sW2[i * 64 + j];
    h[(size_t)n * 64 + j] = tanhf(a2);
}

// ---------------- CSR build ----------------
__global__ void __launch_bounds__(256) hist_kernel(
    const int* __restrict__ dst, int* __restrict__ deg, int E)
{
    const int e = blockIdx.x * 256 + threadIdx.x;
    if (e < E) atomicAdd(&deg[dst[e]], 1);
}

__global__ void __launch_bounds__(256) degsum_kernel(
    const int* __restrict__ deg, int* __restrict__ bsum, int N)
{
    __shared__ int red[256];
    const int t = threadIdx.x;
    const int i = blockIdx.x * 256 + t;
    red[t] = (i < N) ? deg[i] : 0;
    __syncthreads();
    for (int off = 128; off > 0; off >>= 1) {
        if (t < off) red[t] += red[t + off];
        __syncthreads();
    }
    if (t == 0) bsum[blockIdx.x] = red[0];
}

__global__ void __launch_bounds__(256) bscan_kernel(
    const int* __restrict__ bsum, int* __restrict__ boff, int nb)
{
    __shared__ int s[256];
    const int t = threadIdx.x;
    const int v = (t < nb) ? bsum[t] : 0;
    s[t] = v;
    __syncthreads();
    for (int off = 1; off < 256; off <<= 1) {
        const int u = (t >= off) ? s[t - off] : 0;
        __syncthreads();
        s[t] += u;
        __syncthreads();
    }
    if (t < nb) boff[t] = s[t] - v;   // exclusive
}

__global__ void __launch_bounds__(256) rowfill_kernel(
    const int* __restrict__ deg, const int* __restrict__ boff,
    int* __restrict__ rowstart, int* __restrict__ cursor, int N)
{
    __shared__ int s[256];
    const int t = threadIdx.x;
    const int i = blockIdx.x * 256 + t;
    const int d = (i < N) ? deg[i] : 0;
    s[t] = d;
    __syncthreads();
    for (int off = 1; off < 256; off <<= 1) {
        const int u = (t >= off) ? s[t - off] : 0;
        __syncthreads();
        s[t] += u;
        __syncthreads();
    }
    const int excl = s[t] - d + boff[blockIdx.x];
    if (i < N) { rowstart[i] = excl; cursor[i] = excl; }
    if (i == N - 1) rowstart[N] = excl + d;
}

__global__ void __launch_bounds__(256) fill_kernel(
    const int* __restrict__ src, const int* __restrict__ dst,
    const float* __restrict__ ew,
    int* __restrict__ cursor, int* __restrict__ csr_src,
    float* __restrict__ csr_w, int E)
{
    const int e = blockIdx.x * 256 + threadIdx.x;
    if (e < E) {
        const int d = dst[e];
        const int p = atomicAdd(&cursor[d], 1);
        csr_src[p] = src[e];
        csr_w[p]   = ew[e];
    }
}

// ------- fused conv: one wave per node, CSR aggregation (unrolled x4) + 2-layer MLP -------
__global__ void __launch_bounds__(512) conv_kernel(
    const float* __restrict__ h,
    const int* __restrict__ rowstart,
    const int* __restrict__ csr_src, const float* __restrict__ csr_w,
    const float* __restrict__ We_k, const float* __restrict__ be_k,
    const float* __restrict__ W0, const float* __restrict__ b0,
    const float* __restrict__ W1, const float* __restrict__ b1,
    float* __restrict__ hout, int N)
{
    __shared__ float sW0[64 * 64];
    __shared__ float sW1[64 * 64];
    __shared__ float sb0[64], sb1[64];
    const int t = threadIdx.x;
    for (int i = t; i < 4096; i += 512) { sW0[i] = W0[i]; sW1[i] = W1[i]; }
    if (t < 64) { sb0[t] = b0[t]; sb1[t] = b1[t]; }
    __syncthreads();
    const int wave = t >> 6, j = t & 63;
    const int n = blockIdx.x * 8 + wave;
    if (n >= N) return;   // wave-uniform exit

    const float wej = We_k[j], bej = be_k[j];
    float acc = h[(size_t)n * 64 + j];   // self term (eps=0)
    const int start = rowstart[n], end = rowstart[n + 1];
    int p = start;
    for (; p + 4 <= end; p += 4) {
        const int   s0 = csr_src[p],     s1 = csr_src[p + 1];
        const int   s2 = csr_src[p + 2], s3 = csr_src[p + 3];
        const float w0 = csr_w[p],       w1 = csr_w[p + 1];
        const float w2 = csr_w[p + 2],   w3 = csr_w[p + 3];
        const float m0 = h[(size_t)s0 * 64 + j] + w0 * wej + bej;
        const float m1 = h[(size_t)s1 * 64 + j] + w1 * wej + bej;
        const float m2 = h[(size_t)s2 * 64 + j] + w2 * wej + bej;
        const float m3 = h[(size_t)s3 * 64 + j] + w3 * wej + bej;
        acc += fmaxf(m0, 0.f) + fmaxf(m1, 0.f) + fmaxf(m2, 0.f) + fmaxf(m3, 0.f);
    }
    for (; p < end; ++p) {
        const int s = csr_src[p];
        const float m = h[(size_t)s * 64 + j] + csr_w[p] * wej + bej;
        acc += fmaxf(m, 0.f);
    }

    // layer 1: m = lrelu(z@W0+b0)   (all lanes active)
    float a = sb0[j];
    #pragma unroll
    for (int i = 0; i < 64; ++i) a += lane_bcast(acc, i) * sW0[i * 64 + j];
    const float mid = lrelu(a);
    // layer 2: hout = tanh(m@W1+b1)
    float a2 = sb1[j];
    #pragma unroll
    for (int i = 0; i < 64; ++i) a2 += lane_bcast(mid, i) * sW1[i * 64 + j];
    hout[(size_t)n * 64 + j] = tanhf(a2);
}

// ---------------- post MLP: out = tanh(lrelu(h@W0+b0)@W1+b1), out:[N,32] ----------------
__global__ void __launch_bounds__(512) post_kernel(
    const float* __restrict__ h,
    const float* __restrict__ W0, const float* __restrict__ b0,
    const float* __restrict__ W1, const float* __restrict__ b1,
    float* __restrict__ out, int N)
{
    __shared__ float sW0[64 * 64];
    __shared__ float sW1[64 * 32];
    __shared__ float sb0[64], sb1[32];
    const int t = threadIdx.x;
    for (int i = t; i < 64 * 64; i += 512) sW0[i] = W0[i];
    for (int i = t; i < 64 * 32; i += 512) sW1[i] = W1[i];
    if (t < 64) sb0[t] = b0[t];
    if (t < 32) sb1[t] = b1[t];
    __syncthreads();
    const int wave = t >> 6, j = t & 63;
    const int n = blockIdx.x * 8 + wave;
    if (n >= N) return;   // wave-uniform
    const float hv = h[(size_t)n * 64 + j];
    float a = sb0[j];
    #pragma unroll
    for (int i = 0; i < 64; ++i) a += lane_bcast(hv, i) * sW0[i * 64 + j];
    const float mid = lrelu(a);
    // layer 2 computed by ALL lanes (clamped column) so readlane sources stay
    // active; lanes 32..63 duplicate lanes 0..31, only j<32 stores.
    const int jj = j & 31;
    float a2 = sb1[jj];
    #pragma unroll
    for (int i = 0; i < 64; ++i) a2 += lane_bcast(mid, i) * sW1[i * 32 + jj];
    if (j < 32) out[(size_t)n * 32 + j] = tanhf(a2);
}

extern "C" void kernel_launch(void* const* d_in, const int* in_sizes, int n_in,
                              void* d_out, int out_size, void* d_ws, size_t ws_size,
                              hipStream_t stream) {
    const float* x     = (const float*)d_in[0];
    const int*   ei    = (const int*)d_in[1];
    const float* ew    = (const float*)d_in[2];
    const float* Wp_in = (const float*)d_in[3];
    const float* bp_in = (const float*)d_in[4];
    const float* Wp_h  = (const float*)d_in[5];
    const float* bp_h  = (const float*)d_in[6];
    const float* We    = (const float*)d_in[7];   // [3,1,64]
    const float* be    = (const float*)d_in[8];   // [3,64]
    const float* Wm0   = (const float*)d_in[9];   // [3,64,64]
    const float* bm0   = (const float*)d_in[10];  // [3,64]
    const float* Wm1   = (const float*)d_in[11];  // [3,64,64]
    const float* bm1   = (const float*)d_in[12];  // [3,64]
    const float* Wq0   = (const float*)d_in[13];
    const float* bq0   = (const float*)d_in[14];
    const float* Wq1   = (const float*)d_in[15];
    const float* bq1   = (const float*)d_in[16];
    float* out = (float*)d_out;

    const int N = in_sizes[0] / 16;
    const int E = in_sizes[2];
    const int* src = ei;
    const int* dst = ei + E;

    // workspace layout
    float* hA       = (float*)d_ws;                 // N*64
    float* hB       = hA + (size_t)N * 64;          // N*64
    int*   deg      = (int*)(hB + (size_t)N * 64);  // N
    int*   rowstart = deg + N;                      // N+1
    int*   cursor   = rowstart + N + 1;             // N
    int*   bsum     = cursor + N;                   // 256
    int*   boff     = bsum + 256;                   // 256
    int*   csr_src  = boff + 256;                   // E
    float* csr_w    = (float*)(csr_src + E);        // E

    const int eblocks = (E + 255) / 256;
    const int nb      = (N + 255) / 256;
    const int nodeblk = (N + 7) / 8;

    // CSR build (reused by all 3 convs)
    hipMemsetAsync(deg, 0, (size_t)N * sizeof(int), stream);
    hist_kernel<<<eblocks, 256, 0, stream>>>(dst, deg, E);
    degsum_kernel<<<nb, 256, 0, stream>>>(deg, bsum, N);
    bscan_kernel<<<1, 256, 0, stream>>>(bsum, boff, nb);
    rowfill_kernel<<<nb, 256, 0, stream>>>(deg, boff, rowstart, cursor, N);
    fill_kernel<<<eblocks, 256, 0, stream>>>(src, dst, ew, cursor, csr_src, csr_w, E);

    prep_kernel<<<nodeblk, 512, 0, stream>>>(x, Wp_in, bp_in, Wp_h, bp_h, hA, N);

    float* hin = hA;
    float* hout = hB;
    for (int k = 0; k < 3; ++k) {
        conv_kernel<<<nodeblk, 512, 0, stream>>>(
            hin, rowstart, csr_src, csr_w,
            We + (size_t)k * 64, be + (size_t)k * 64,
            Wm0 + (size_t)k * 4096, bm0 + (size_t)k * 64,
            Wm1 + (size_t)k * 4096, bm1 + (size_t)k * 64, hout, N);
        float* tmp = hin; hin = hout; hout = tmp;
    }

    post_kernel<<<nodeblk, 512, 0, stream>>>(hin, Wq0, bq0, Wq1, bq1, out, N);
}